// Round 3
// baseline (405.288 us; speedup 1.0000x reference)
//
#include <hip/hip_runtime.h>
#include <hip/hip_cooperative_groups.h>

namespace cg = cooperative_groups;

// Problem constants (from reference setup_inputs)
#define B_ 64
#define C_ 256
#define T_ 2048
#define EPS_ 1e-4f
#define NPC ((float)(B_ * T_))   // elements per channel = 131072
#define T4 (T_ / 4)              // 512 vec4 per (b,c) row

#define SPLITS 4                 // batch splits for stats partials
#define BPB (B_ / SPLITS)        // 16 batch rows per stats block
#define NBLK 1024                // grid size (4 blocks/CU on 256 CUs)

typedef float f4 __attribute__((ext_vector_type(4)));

// ---------------------------------------------------------------------------
// Phase 1: per-channel partial sum & sumsq. Block (c,s) reduces BPB batch
// rows of channel c, fully coalesced f4 loads, writes 2 disjoint partials.
// partials layout: [s][c] sums at [0,SPLITS*C_), sumsq at [SPLITS*C_, 2*...).
// ---------------------------------------------------------------------------
__device__ __forceinline__ void stats_phase(const float* __restrict__ x,
                                            float* __restrict__ partials,
                                            int blk, int tid) {
    const int c = blk & (C_ - 1);
    const int s = blk >> 8;
    float sum = 0.0f, sumsq = 0.0f;
    const int b0 = s * BPB;
    #pragma unroll 4
    for (int b = 0; b < BPB; ++b) {
        const f4* p = (const f4*)(x + (size_t)(b0 + b) * (C_ * T_) + (size_t)c * T_);
        #pragma unroll
        for (int i = 0; i < T4 / 256; ++i) {       // 2 f4 per thread per row
            f4 v = p[tid + i * 256];
            sum   += v.x + v.y + v.z + v.w;
            sumsq += v.x * v.x + v.y * v.y + v.z * v.z + v.w * v.w;
        }
    }
    #pragma unroll
    for (int off = 32; off > 0; off >>= 1) {
        sum   += __shfl_down(sum, off);
        sumsq += __shfl_down(sumsq, off);
    }
    __shared__ float ls[4], lss[4];
    const int wave = tid >> 6, lane = tid & 63;
    if (lane == 0) { ls[wave] = sum; lss[wave] = sumsq; }
    __syncthreads();
    if (tid == 0) {
        partials[s * C_ + c]               = ls[0] + ls[1] + ls[2] + ls[3];
        partials[SPLITS * C_ + s * C_ + c] = lss[0] + lss[1] + lss[2] + lss[3];
        __threadfence();   // device-scope: visible across XCDs before grid sync
    }
}

// ---------------------------------------------------------------------------
// Phase 2: finalize + normalize. Block q covers ONE channel c = q>>1 and half
// its t-range; thread owns one (c,t4) vec4 and streams 32 batch rows with the
// affine held in registers. gamma/beta [T,C] read directly (L2-hot, amortized
// 32x). NT stores keep x L3-resident.
// ---------------------------------------------------------------------------
__device__ __forceinline__ void norm_phase(const float* __restrict__ x,
                                           const float* __restrict__ gamma,
                                           const float* __restrict__ beta,
                                           const float* __restrict__ partials,
                                           float* __restrict__ out,
                                           int blk, int tid) {
    const int half = blk >> 9;                 // which 32-batch half
    const int q    = blk & 511;
    const int c    = q >> 1;                   // block-uniform channel
    const int t4   = (q & 1) * 256 + tid;
    const int t    = t4 * 4;

    float S = 0.0f, SS = 0.0f;
    #pragma unroll
    for (int s = 0; s < SPLITS; ++s) {         // block-uniform -> scalar loads
        S  += partials[s * C_ + c];
        SS += partials[SPLITS * C_ + s * C_ + c];
    }
    const float mean = S / NPC;
    const float istd = rsqrtf(SS / NPC - mean * mean + EPS_);

    f4 sc, sh;
    #pragma unroll
    for (int j = 0; j < 4; ++j) {
        float g  = gamma[(size_t)(t + j) * C_ + c];
        float bb = beta [(size_t)(t + j) * C_ + c];
        float s1 = g * istd;
        ((float*)&sc)[j] = s1;
        ((float*)&sh)[j] = fmaf(-mean, s1, bb);
    }

    size_t idx = (size_t)((half * (B_ / 2)) * C_ + c) * T4 + t4;
    const size_t step = (size_t)C_ * T4;       // one batch row
    #pragma unroll 4
    for (int b = 0; b < B_ / 2; ++b) {
        f4 xv = ((const f4*)x)[idx];
        f4 o;
        o.x = fmaf(xv.x, sc.x, sh.x);
        o.y = fmaf(xv.y, sc.y, sh.y);
        o.z = fmaf(xv.z, sc.z, sh.z);
        o.w = fmaf(xv.w, sc.w, sh.w);
        __builtin_nontemporal_store(o, &((f4*)out)[idx]);
        idx += step;
    }
}

// ---------------------------------------------------------------------------
// Fused cooperative kernel: stats -> grid.sync -> normalize. 1024 blocks of
// 256; launch_bounds(256,4) guarantees VGPR<=128 so 4 blocks/CU are resident.
// ---------------------------------------------------------------------------
__global__ __launch_bounds__(256, 4) void bntt_fused(const float* __restrict__ x,
                                                     const float* __restrict__ gamma,
                                                     const float* __restrict__ beta,
                                                     float* __restrict__ partials,
                                                     float* __restrict__ out) {
    stats_phase(x, partials, blockIdx.x, threadIdx.x);
    cg::this_grid().sync();
    norm_phase(x, gamma, beta, partials, out, blockIdx.x, threadIdx.x);
}

// Fallback pair (identical math) if cooperative launch is unavailable.
__global__ __launch_bounds__(256, 4) void bntt_stats_k(const float* __restrict__ x,
                                                       float* __restrict__ partials) {
    stats_phase(x, partials, blockIdx.x, threadIdx.x);
}
__global__ __launch_bounds__(256, 4) void bntt_norm_k(const float* __restrict__ x,
                                                      const float* __restrict__ gamma,
                                                      const float* __restrict__ beta,
                                                      const float* __restrict__ partials,
                                                      float* __restrict__ out) {
    norm_phase(x, gamma, beta, partials, out, blockIdx.x, threadIdx.x);
}

extern "C" void kernel_launch(void* const* d_in, const int* in_sizes, int n_in,
                              void* d_out, int out_size, void* d_ws, size_t ws_size,
                              hipStream_t stream) {
    const float* x     = (const float*)d_in[0];
    const float* gamma = (const float*)d_in[1];
    const float* beta  = (const float*)d_in[2];
    float* out      = (float*)d_out;
    float* partials = (float*)d_ws;            // 2*SPLITS*C_ = 2048 floats

    void* args[] = {(void*)&x, (void*)&gamma, (void*)&beta,
                    (void*)&partials, (void*)&out};
    hipError_t e = hipLaunchCooperativeKernel((const void*)bntt_fused,
                                              dim3(NBLK), dim3(256),
                                              args, 0, stream);
    if (e != hipSuccess) {
        // Non-cooperative fallback: two plain launches, same math.
        bntt_stats_k<<<NBLK, 256, 0, stream>>>(x, partials);
        bntt_norm_k<<<NBLK, 256, 0, stream>>>(x, gamma, beta, partials, out);
    }
}